// Round 11
// baseline (406.466 us; speedup 1.0000x reference)
//
#include <hip/hip_runtime.h>

// Scaled-dot-product attention, bs=4, h=16, S=2048, D=64, f32 in/out.
// Outputs O [64,2048,64] and P=attn_weights [64,2048,2048] (f32, 1.07 GB write).
// Confirmed levers: full-128B-line stores via LDS transpose (R7, +13%);
// nontemporal full-line P stores bypass L2 write-allocate (R10, +25%).
// R11: remove K/V reg prefetch (R5/R6: proven null) -> VGPR under 128 ->
// __launch_bounds__(256,4): all 4 blocks/CU resident, no 1/4-machine tail
// round. nt on O stores too.

#define S_LEN 2048
#define DH 64
#define NHEADS 64  // bs*h

typedef short short8 __attribute__((ext_vector_type(8)));   // 8 x bf16
typedef float f32x4 __attribute__((ext_vector_type(4)));
typedef float f32x16 __attribute__((ext_vector_type(16)));
typedef unsigned short u16;

__device__ __forceinline__ u16 f2bf(float f) {
  union { float f; unsigned u; } x;
  x.f = f;
  unsigned r = x.u + 0x7fffu + ((x.u >> 16) & 1u);  // RNE
  return (u16)(r >> 16);
}

__device__ __forceinline__ unsigned pkbf(float a, float b) {
  return (unsigned)f2bf(a) | ((unsigned)f2bf(b) << 16);  // a -> low, b -> high
}

// v_permlane32_swap_b32: new a[32+i]=old b[i]; new b[i]=old a[32+i]
__device__ __forceinline__ void plswap(unsigned& a, unsigned& b) {
  asm("v_permlane32_swap_b32 %0, %1" : "+v"(a), "+v"(b));
}

// ---- pre-pass: Q * scale -> bf16, same layout ----
__global__ __launch_bounds__(256) void cvt_scale_k(const float* __restrict__ in,
                                                   u16* __restrict__ out,
                                                   float scale, int n4) {
  int i = blockIdx.x * 256 + threadIdx.x;
  if (i >= n4) return;
  float4 v = ((const float4*)in)[i];
  union { u16 s[4]; unsigned long long ll; } o;
  o.s[0] = f2bf(v.x * scale); o.s[1] = f2bf(v.y * scale);
  o.s[2] = f2bf(v.z * scale); o.s[3] = f2bf(v.w * scale);
  ((unsigned long long*)out)[i] = o.ll;
}

// ---- pre-pass: per-head transpose [R][C] f32 -> [C][R] bf16 ----
__global__ __launch_bounds__(256) void transpose_cvt_k(const float* __restrict__ in,
                                                       u16* __restrict__ out,
                                                       int R, int C) {
  __shared__ float tile[64][65];
  const int tilesC = C >> 6;
  const int tilesPerHead = (R >> 6) * tilesC;
  int hb = blockIdx.x;
  int head = hb / tilesPerHead;
  int t = hb - head * tilesPerHead;
  int tr = t / tilesC, tc = t - tr * tilesC;
  const float* ip = in + (size_t)head * R * C + (size_t)tr * 64 * C + (size_t)tc * 64;
  u16* op = out + (size_t)head * R * C + (size_t)tc * 64 * R + (size_t)tr * 64;
  int c = threadIdx.x & 63, r0 = threadIdx.x >> 6;
#pragma unroll
  for (int k = 0; k < 16; ++k) {
    int r = (k << 2) + r0;
    tile[r][c] = ip[(size_t)r * C + c];
  }
  __syncthreads();
#pragma unroll
  for (int k = 0; k < 16; ++k) {
    int orow = (k << 2) + r0;
    op[(size_t)orow * R + c] = f2bf(tile[c][orow]);
  }
}

// ---- fused attention, swapped 32x32, LDS-transposed full-line nt stores ----
// Layouts (bf16): Qb [h][s][d] (pre-scaled), Kn [h][s][d], Vt [h][d][s].
// Block = 128 q-rows = 4 waves x 32. Per wave, j-tiles of 32.
// mfma_f32_32x32x16_bf16:  A row=lane&31, k=(lane>>5)*8+i (8 contig)
//                          B col=lane&31, k=(lane>>5)*8+i
//                          D col=lane&31, row=(r&3)+8*(r>>2)+4*(lane>>5)
__global__ __launch_bounds__(256, 4) void attn_k(const u16* __restrict__ Qb,
                                                 const u16* __restrict__ Kn,
                                                 const u16* __restrict__ Vt,
                                                 float* __restrict__ Og,
                                                 float* __restrict__ Pg) {
  // per-wave 32x32 f32 transpose tile; row stride 32 floats (128 B).
  __shared__ float tile[4][32 * 32];
  int bid = blockIdx.x;
  // bijective XCD swizzle: 1024 blocks, XCD x gets heads 8x..8x+7 (K+V = 4MB = L2)
  int work = ((bid & 7) << 7) | (bid >> 3);
  int head = work >> 4;
  int rblk = work & 15;
  int lane = threadIdx.x & 63;
  int wv = threadIdx.x >> 6;
  int q = lane & 31;
  int hi = lane >> 5;
  int q0 = (rblk << 7) + (wv << 5);
  float* tw = tile[wv];
  int rq = lane >> 3;   // 0..7: row-within-group for coalesced store reads
  int rc = lane & 7;    // 0..7: 16B chunk index within the 128B line

  // Q B-fragments, resident
  const u16* qp = Qb + (size_t)(head * S_LEN + q0 + q) * DH + hi * 8;
  short8 qf0 = *(const short8*)(qp);
  short8 qf1 = *(const short8*)(qp + 16);
  short8 qf2 = *(const short8*)(qp + 32);
  short8 qf3 = *(const short8*)(qp + 48);

  const u16* kp = Kn + (size_t)head * S_LEN * DH + (size_t)q * DH + hi * 8;
  const u16* vp = Vt + (size_t)head * DH * S_LEN + (size_t)q * S_LEN + hi * 8;

  // ---- pass 1: l[q] = sum_j exp(s) ----
  float ls0 = 0.f, ls1 = 0.f, ls2 = 0.f, ls3 = 0.f;
  for (int j0 = 0; j0 < S_LEN; j0 += 32) {
    const u16* kb = kp + (size_t)j0 * DH;
    short8 k0 = *(const short8*)(kb);
    short8 k1 = *(const short8*)(kb + 16);
    short8 k2 = *(const short8*)(kb + 32);
    short8 k3 = *(const short8*)(kb + 48);
    f32x16 s = {};
    s = __builtin_amdgcn_mfma_f32_32x32x16_bf16(k0, qf0, s, 0, 0, 0);
    s = __builtin_amdgcn_mfma_f32_32x32x16_bf16(k1, qf1, s, 0, 0, 0);
    s = __builtin_amdgcn_mfma_f32_32x32x16_bf16(k2, qf2, s, 0, 0, 0);
    s = __builtin_amdgcn_mfma_f32_32x32x16_bf16(k3, qf3, s, 0, 0, 0);
#pragma unroll
    for (int r = 0; r < 16; r += 4) {
      ls0 += __expf(s[r]);
      ls1 += __expf(s[r + 1]);
      ls2 += __expf(s[r + 2]);
      ls3 += __expf(s[r + 3]);
    }
  }
  float ls = (ls0 + ls1) + (ls2 + ls3);
  ls += __shfl_xor(ls, 32);  // combine hi/lo halves (disjoint j subsets)
  float rl = 1.f / ls;

  // ---- pass 2: coalesced nt P write + O = P*V ----
  f32x16 oa = {}, ob = {};
  float* pbW = Pg + (size_t)(head * S_LEN + q0) * S_LEN;

  for (int j0 = 0; j0 < S_LEN; j0 += 32) {
    const u16* kb = kp + (size_t)j0 * DH;
    short8 k0 = *(const short8*)(kb);
    short8 k1 = *(const short8*)(kb + 16);
    short8 k2 = *(const short8*)(kb + 32);
    short8 k3 = *(const short8*)(kb + 48);
    const u16* vj = vp + j0;
    short8 v0 = *(const short8*)(vj);                     // jstep0, d 0..31
    short8 v1 = *(const short8*)(vj + 16);                // jstep1, d 0..31
    short8 v2 = *(const short8*)(vj + 32 * S_LEN);        // jstep0, d 32..63
    short8 v3 = *(const short8*)(vj + 32 * S_LEN + 16);   // jstep1, d 32..63

    f32x16 s = {};
    s = __builtin_amdgcn_mfma_f32_32x32x16_bf16(k0, qf0, s, 0, 0, 0);
    s = __builtin_amdgcn_mfma_f32_32x32x16_bf16(k1, qf1, s, 0, 0, 0);
    s = __builtin_amdgcn_mfma_f32_32x32x16_bf16(k2, qf2, s, 0, 0, 0);
    s = __builtin_amdgcn_mfma_f32_32x32x16_bf16(k3, qf3, s, 0, 0, 0);

    float p[16];
#pragma unroll
    for (int r = 0; r < 16; ++r) p[r] = __expf(s[r]) * rl;

    // LDS transpose write: lane holds column q, regs 4g..4g+3 = j-chunk c=2g+hi.
    // chunk-XOR swizzle keeps the column-write ~4-way instead of 32-way.
#pragma unroll
    for (int g = 0; g < 4; ++g) {
      int phys = (2 * g + hi) ^ (q & 7);
      f32x4 w = {p[4 * g], p[4 * g + 1], p[4 * g + 2], p[4 * g + 3]};
      *(f32x4*)&tw[q * 32 + phys * 4] = w;
    }

    // T12 redistribute from regs (independent of LDS): D-layout -> A-frag
    unsigned A0 = pkbf(p[0], p[1]),   A1 = pkbf(p[2], p[3]);
    unsigned B0 = pkbf(p[4], p[5]),   B1 = pkbf(p[6], p[7]);
    plswap(A0, B0);
    plswap(A1, B1);
    unsigned C0 = pkbf(p[8], p[9]),   C1 = pkbf(p[10], p[11]);
    unsigned D0 = pkbf(p[12], p[13]), D1 = pkbf(p[14], p[15]);
    plswap(C0, D0);
    plswap(C1, D1);
    union { unsigned w[4]; short8 v; } pa0u = {{A0, A1, B0, B1}};
    union { unsigned w[4]; short8 v; } pa1u = {{C0, C1, D0, D1}};

    oa = __builtin_amdgcn_mfma_f32_32x32x16_bf16(pa0u.v, v0, oa, 0, 0, 0);
    oa = __builtin_amdgcn_mfma_f32_32x32x16_bf16(pa1u.v, v1, oa, 0, 0, 0);
    ob = __builtin_amdgcn_mfma_f32_32x32x16_bf16(pa0u.v, v2, ob, 0, 0, 0);
    ob = __builtin_amdgcn_mfma_f32_32x32x16_bf16(pa1u.v, v3, ob, 0, 0, 0);

    // LDS read back + FULL-LINE nontemporal P stores:
    // 8 lanes x 16B = one whole 128B line -> streams to HBM, no L2 allocate.
    float* ps = pbW + j0;
#pragma unroll
    for (int g = 0; g < 4; ++g) {
      int qi = 8 * g + rq;
      int phys = rc ^ (qi & 7);
      f32x4 v = *(const f32x4*)&tw[qi * 32 + phys * 4];
      __builtin_nontemporal_store(v, (f32x4*)(ps + (size_t)qi * S_LEN + rc * 4));
    }
  }

  // ---- O epilogue: LDS transpose -> full-line nt stores ----
  float* ogb = Og + (size_t)(head * S_LEN + q0) * DH;
#pragma unroll
  for (int r = 0; r < 16; ++r) {
    int qi = (r & 3) + 8 * (r >> 2) + 4 * hi;
    tw[qi * 32 + q] = oa[r];   // bank = q -> conflict-free
  }
#pragma unroll
  for (int g = 0; g < 4; ++g) {
    int qi = 8 * g + rq;
    f32x4 v = *(const f32x4*)&tw[qi * 32 + rc * 4];
    __builtin_nontemporal_store(v, (f32x4*)(ogb + (size_t)qi * DH + rc * 4));
  }
#pragma unroll
  for (int r = 0; r < 16; ++r) {
    int qi = (r & 3) + 8 * (r >> 2) + 4 * hi;
    tw[qi * 32 + q] = ob[r];
  }
#pragma unroll
  for (int g = 0; g < 4; ++g) {
    int qi = 8 * g + rq;
    f32x4 v = *(const f32x4*)&tw[qi * 32 + rc * 4];
    __builtin_nontemporal_store(v, (f32x4*)(ogb + (size_t)qi * DH + 32 + rc * 4));
  }
}

extern "C" void kernel_launch(void* const* d_in, const int* in_sizes, int n_in,
                              void* d_out, int out_size, void* d_ws, size_t ws_size,
                              hipStream_t stream) {
  const float* q = (const float*)d_in[0];
  const float* k = (const float*)d_in[1];  // [b,h,d,s]
  const float* v = (const float*)d_in[2];  // [b,h,s,d]
  float* Og = (float*)d_out;
  float* Pg = Og + (size_t)NHEADS * S_LEN * DH;

  const size_t elems = (size_t)NHEADS * S_LEN * DH;  // 8,388,608
  u16* Qb = (u16*)d_ws;           // bf16 [h][s][d], pre-scaled
  u16* Kn = Qb + elems;           // bf16 [h][s][d]
  u16* Vt = Kn + elems;           // bf16 [h][d][s]

  int n4 = (int)(elems / 4);
  cvt_scale_k<<<n4 / 256, 256, 0, stream>>>(q, Qb, 0.125f, n4);
  transpose_cvt_k<<<NHEADS * (S_LEN / 64), 256, 0, stream>>>(k, Kn, DH, S_LEN);
  transpose_cvt_k<<<NHEADS * (S_LEN / 64), 256, 0, stream>>>(v, Vt, S_LEN, DH);
  attn_k<<<NHEADS * (S_LEN / 128), 256, 0, stream>>>(Qb, Kn, Vt, Og, Pg);
}

// Round 12
// 404.259 us; speedup vs baseline: 1.0055x; 1.0055x over previous
//
#include <hip/hip_runtime.h>

// Scaled-dot-product attention, bs=4, h=16, S=2048, D=64, f32 in/out.
// Outputs O [64,2048,64] and P=attn_weights [64,2048,2048] (f32, 1.07 GB write).
// Confirmed levers (A/B): full-128B-line stores via LDS transpose (R7 +13%);
// nontemporal full-line P stores bypassing L2 write-allocate (R10 +25%).
// R12: R9's DRAM-page-burst idea REQUIRED nt to reach the DRAM (R9 was null
// only because L2 filtered the pattern). Accumulate JSPAN=128 j-columns per
// wave in LDS [32][132], then nt-burst 32 rows x 512B contiguous (4 lines per
// page activation instead of 1).

#define S_LEN 2048
#define DH 64
#define NHEADS 64  // bs*h

typedef short short8 __attribute__((ext_vector_type(8)));   // 8 x bf16
typedef float f32x4 __attribute__((ext_vector_type(4)));
typedef float f32x16 __attribute__((ext_vector_type(16)));
typedef unsigned short u16;

__device__ __forceinline__ u16 f2bf(float f) {
  union { float f; unsigned u; } x;
  x.f = f;
  unsigned r = x.u + 0x7fffu + ((x.u >> 16) & 1u);  // RNE
  return (u16)(r >> 16);
}

__device__ __forceinline__ unsigned pkbf(float a, float b) {
  return (unsigned)f2bf(a) | ((unsigned)f2bf(b) << 16);  // a -> low, b -> high
}

// v_permlane32_swap_b32: new a[32+i]=old b[i]; new b[i]=old a[32+i]
__device__ __forceinline__ void plswap(unsigned& a, unsigned& b) {
  asm("v_permlane32_swap_b32 %0, %1" : "+v"(a), "+v"(b));
}

// ---- pre-pass: Q * scale -> bf16, same layout ----
__global__ __launch_bounds__(256) void cvt_scale_k(const float* __restrict__ in,
                                                   u16* __restrict__ out,
                                                   float scale, int n4) {
  int i = blockIdx.x * 256 + threadIdx.x;
  if (i >= n4) return;
  float4 v = ((const float4*)in)[i];
  union { u16 s[4]; unsigned long long ll; } o;
  o.s[0] = f2bf(v.x * scale); o.s[1] = f2bf(v.y * scale);
  o.s[2] = f2bf(v.z * scale); o.s[3] = f2bf(v.w * scale);
  ((unsigned long long*)out)[i] = o.ll;
}

// ---- pre-pass: per-head transpose [R][C] f32 -> [C][R] bf16 ----
__global__ __launch_bounds__(256) void transpose_cvt_k(const float* __restrict__ in,
                                                       u16* __restrict__ out,
                                                       int R, int C) {
  __shared__ float tile[64][65];
  const int tilesC = C >> 6;
  const int tilesPerHead = (R >> 6) * tilesC;
  int hb = blockIdx.x;
  int head = hb / tilesPerHead;
  int t = hb - head * tilesPerHead;
  int tr = t / tilesC, tc = t - tr * tilesC;
  const float* ip = in + (size_t)head * R * C + (size_t)tr * 64 * C + (size_t)tc * 64;
  u16* op = out + (size_t)head * R * C + (size_t)tc * 64 * R + (size_t)tr * 64;
  int c = threadIdx.x & 63, r0 = threadIdx.x >> 6;
#pragma unroll
  for (int k = 0; k < 16; ++k) {
    int r = (k << 2) + r0;
    tile[r][c] = ip[(size_t)r * C + c];
  }
  __syncthreads();
#pragma unroll
  for (int k = 0; k < 16; ++k) {
    int orow = (k << 2) + r0;
    op[(size_t)orow * R + c] = f2bf(tile[c][orow]);
  }
}

// ---- fused attention, swapped 32x32, JSPAN-128 nt burst stores ----
// Layouts (bf16): Qb [h][s][d] (pre-scaled), Kn [h][s][d], Vt [h][d][s].
// Block = 128 q-rows = 4 waves x 32. Per wave, j-tiles of 32, bursts of 128.
// mfma_f32_32x32x16_bf16:  A row=lane&31, k=(lane>>5)*8+i (8 contig)
//                          B col=lane&31, k=(lane>>5)*8+i
//                          D col=lane&31, row=(r&3)+8*(r>>2)+4*(lane>>5)
__global__ __launch_bounds__(256, 2) void attn_k(const u16* __restrict__ Qb,
                                                 const u16* __restrict__ Kn,
                                                 const u16* __restrict__ Vt,
                                                 float* __restrict__ Og,
                                                 float* __restrict__ Pg) {
  // per-wave 32 x 128 f32 panel, row stride 132 (bank = 4row+4chunk+i spread)
  __shared__ float tile[4][32 * 132];
  int bid = blockIdx.x;
  // bijective XCD swizzle: 1024 blocks, XCD x gets heads 8x..8x+7 (K+V = 4MB = L2)
  int work = ((bid & 7) << 7) | (bid >> 3);
  int head = work >> 4;
  int rblk = work & 15;
  int lane = threadIdx.x & 63;
  int wv = threadIdx.x >> 6;
  int q = lane & 31;
  int hi = lane >> 5;
  int q0 = (rblk << 7) + (wv << 5);
  float* tw = tile[wv];
  int sl = lane >> 5;   // 0/1: row parity for burst stores
  int jl = lane & 31;   // 16B chunk within the 512B row span
  int rq = lane >> 3;   // epilogue helpers
  int rc = lane & 7;

  // Q B-fragments, resident
  const u16* qp = Qb + (size_t)(head * S_LEN + q0 + q) * DH + hi * 8;
  short8 qf0 = *(const short8*)(qp);
  short8 qf1 = *(const short8*)(qp + 16);
  short8 qf2 = *(const short8*)(qp + 32);
  short8 qf3 = *(const short8*)(qp + 48);

  const u16* kp = Kn + (size_t)head * S_LEN * DH + (size_t)q * DH + hi * 8;
  const u16* vp = Vt + (size_t)head * DH * S_LEN + (size_t)q * S_LEN + hi * 8;

  // ---- pass 1: l[q] = sum_j exp(s) ----
  float ls0 = 0.f, ls1 = 0.f, ls2 = 0.f, ls3 = 0.f;
  for (int j0 = 0; j0 < S_LEN; j0 += 32) {
    const u16* kb = kp + (size_t)j0 * DH;
    short8 k0 = *(const short8*)(kb);
    short8 k1 = *(const short8*)(kb + 16);
    short8 k2 = *(const short8*)(kb + 32);
    short8 k3 = *(const short8*)(kb + 48);
    f32x16 s = {};
    s = __builtin_amdgcn_mfma_f32_32x32x16_bf16(k0, qf0, s, 0, 0, 0);
    s = __builtin_amdgcn_mfma_f32_32x32x16_bf16(k1, qf1, s, 0, 0, 0);
    s = __builtin_amdgcn_mfma_f32_32x32x16_bf16(k2, qf2, s, 0, 0, 0);
    s = __builtin_amdgcn_mfma_f32_32x32x16_bf16(k3, qf3, s, 0, 0, 0);
#pragma unroll
    for (int r = 0; r < 16; r += 4) {
      ls0 += __expf(s[r]);
      ls1 += __expf(s[r + 1]);
      ls2 += __expf(s[r + 2]);
      ls3 += __expf(s[r + 3]);
    }
  }
  float ls = (ls0 + ls1) + (ls2 + ls3);
  ls += __shfl_xor(ls, 32);  // combine hi/lo halves (disjoint j subsets)
  float rl = 1.f / ls;

  // ---- pass 2: panel-accumulated nt burst P write + O = P*V ----
  f32x16 oa = {}, ob = {};
  float* pbW = Pg + (size_t)(head * S_LEN + q0) * S_LEN;

  for (int jb = 0; jb < S_LEN; jb += 128) {
#pragma unroll
    for (int jt = 0; jt < 4; ++jt) {
      int j0 = jb + (jt << 5);
      const u16* kb = kp + (size_t)j0 * DH;
      short8 k0 = *(const short8*)(kb);
      short8 k1 = *(const short8*)(kb + 16);
      short8 k2 = *(const short8*)(kb + 32);
      short8 k3 = *(const short8*)(kb + 48);
      const u16* vj = vp + j0;
      short8 v0 = *(const short8*)(vj);                     // jstep0, d 0..31
      short8 v1 = *(const short8*)(vj + 16);                // jstep1, d 0..31
      short8 v2 = *(const short8*)(vj + 32 * S_LEN);        // jstep0, d 32..63
      short8 v3 = *(const short8*)(vj + 32 * S_LEN + 16);   // jstep1, d 32..63

      f32x16 s = {};
      s = __builtin_amdgcn_mfma_f32_32x32x16_bf16(k0, qf0, s, 0, 0, 0);
      s = __builtin_amdgcn_mfma_f32_32x32x16_bf16(k1, qf1, s, 0, 0, 0);
      s = __builtin_amdgcn_mfma_f32_32x32x16_bf16(k2, qf2, s, 0, 0, 0);
      s = __builtin_amdgcn_mfma_f32_32x32x16_bf16(k3, qf3, s, 0, 0, 0);

      float p[16];
#pragma unroll
      for (int r = 0; r < 16; ++r) p[r] = __expf(s[r]) * rl;

      // transposed panel write: lane q, cols jt*32 + 8g + 4hi (4 contig j)
#pragma unroll
      for (int g = 0; g < 4; ++g) {
        f32x4 w = {p[4 * g], p[4 * g + 1], p[4 * g + 2], p[4 * g + 3]};
        *(f32x4*)&tw[q * 132 + (jt << 5) + 8 * g + 4 * hi] = w;
      }

      // T12 redistribute from regs: D-layout -> A-frag (k = hi*8+i contiguous j)
      unsigned A0 = pkbf(p[0], p[1]),   A1 = pkbf(p[2], p[3]);
      unsigned B0 = pkbf(p[4], p[5]),   B1 = pkbf(p[6], p[7]);
      plswap(A0, B0);
      plswap(A1, B1);
      unsigned C0 = pkbf(p[8], p[9]),   C1 = pkbf(p[10], p[11]);
      unsigned D0 = pkbf(p[12], p[13]), D1 = pkbf(p[14], p[15]);
      plswap(C0, D0);
      plswap(C1, D1);
      union { unsigned w[4]; short8 v; } pa0u = {{A0, A1, B0, B1}};
      union { unsigned w[4]; short8 v; } pa1u = {{C0, C1, D0, D1}};

      oa = __builtin_amdgcn_mfma_f32_32x32x16_bf16(pa0u.v, v0, oa, 0, 0, 0);
      oa = __builtin_amdgcn_mfma_f32_32x32x16_bf16(pa1u.v, v1, oa, 0, 0, 0);
      ob = __builtin_amdgcn_mfma_f32_32x32x16_bf16(pa0u.v, v2, ob, 0, 0, 0);
      ob = __builtin_amdgcn_mfma_f32_32x32x16_bf16(pa1u.v, v3, ob, 0, 0, 0);
    }

    // nt burst: 32 rows x 512 B contiguous each (4 lines per DRAM page hit)
    float* ps = pbW + jb;
#pragma unroll
    for (int rr = 0; rr < 16; ++rr) {
      int row = 2 * rr + sl;
      f32x4 v = *(const f32x4*)&tw[row * 132 + jl * 4];
      __builtin_nontemporal_store(v, (f32x4*)(ps + (size_t)row * S_LEN + jl * 4));
    }
  }

  // ---- O epilogue: panel transpose (stride 132) -> full-line nt stores ----
  float* ogb = Og + (size_t)(head * S_LEN + q0) * DH;
#pragma unroll
  for (int r = 0; r < 16; ++r) {
    int qi = (r & 3) + 8 * (r >> 2) + 4 * hi;
    tw[qi * 132 + q] = oa[r];
  }
#pragma unroll
  for (int g = 0; g < 4; ++g) {
    int qi = 8 * g + rq;
    f32x4 v = *(const f32x4*)&tw[qi * 132 + rc * 4];
    __builtin_nontemporal_store(v, (f32x4*)(ogb + (size_t)qi * DH + rc * 4));
  }
#pragma unroll
  for (int r = 0; r < 16; ++r) {
    int qi = (r & 3) + 8 * (r >> 2) + 4 * hi;
    tw[qi * 132 + q] = ob[r];
  }
#pragma unroll
  for (int g = 0; g < 4; ++g) {
    int qi = 8 * g + rq;
    f32x4 v = *(const f32x4*)&tw[qi * 132 + rc * 4];
    __builtin_nontemporal_store(v, (f32x4*)(ogb + (size_t)qi * DH + 32 + rc * 4));
  }
}

extern "C" void kernel_launch(void* const* d_in, const int* in_sizes, int n_in,
                              void* d_out, int out_size, void* d_ws, size_t ws_size,
                              hipStream_t stream) {
  const float* q = (const float*)d_in[0];
  const float* k = (const float*)d_in[1];  // [b,h,d,s]
  const float* v = (const float*)d_in[2];  // [b,h,s,d]
  float* Og = (float*)d_out;
  float* Pg = Og + (size_t)NHEADS * S_LEN * DH;

  const size_t elems = (size_t)NHEADS * S_LEN * DH;  // 8,388,608
  u16* Qb = (u16*)d_ws;           // bf16 [h][s][d], pre-scaled
  u16* Kn = Qb + elems;           // bf16 [h][s][d]
  u16* Vt = Kn + elems;           // bf16 [h][d][s]

  int n4 = (int)(elems / 4);
  cvt_scale_k<<<n4 / 256, 256, 0, stream>>>(q, Qb, 0.125f, n4);
  transpose_cvt_k<<<NHEADS * (S_LEN / 64), 256, 0, stream>>>(k, Kn, DH, S_LEN);
  transpose_cvt_k<<<NHEADS * (S_LEN / 64), 256, 0, stream>>>(v, Vt, S_LEN, DH);
  attn_k<<<NHEADS * (S_LEN / 128), 256, 0, stream>>>(Qb, Kn, Vt, Og, Pg);
}